// Round 5
// baseline (903.290 us; speedup 1.0000x reference)
//
#include <hip/hip_runtime.h>
#include <cstdint>
#include <cstddef>

// AnimaMLP: router(top-5 of 8, softmax/e) + 8 dense experts (silu(xWg)*xWu)Wd,
// signed-weighted sum, plus mean(output^2) scalar.
//
// Expert-chunked 8-phase plan (fits round-1 ws footprint, 201.6MB):
//   pass p in {0,1}: experts 4p..4p+3
//     gemm1_8p (persistent, 256 blocks x 4 items): H'[8192 x 4096]
//     gemm2_8p: out (+)= H' @ Wdt[:, 4096p..]  (BM=BN=256, K=4096)
// ws map (bytes):
//   0         Xb   bf16 8192x2048   33,554,432
//   33554432  Wgt  bf16 8x1024x2048 33,554,432   (Wg^T per expert, k-contig)
//   67108864  Wut  bf16             33,554,432
//   100663296 Wdt  bf16 2048x8192   33,554,432   (Wd^T, k-contig)
//   134217728 H'   bf16 8192x4096   67,108,864   (one expert-halfpass)
//   201326592 CwT  f32  8 x 8192       262,144   (c[e][row], signed)
//   201588736 part f32  1024             4,096   -> total 201,592,832

typedef short bf16x8 __attribute__((ext_vector_type(8)));
typedef float f32x4 __attribute__((ext_vector_type(4)));
typedef unsigned short u16;

typedef const unsigned int __attribute__((address_space(1)))* as1_u32p;
typedef unsigned int __attribute__((address_space(3)))* as3_u32p;

#define VMCNT6 asm volatile("s_waitcnt vmcnt(6)" ::: "memory")
#define VMCNT0 asm volatile("s_waitcnt vmcnt(0)" ::: "memory")
#define LGKM0  asm volatile("s_waitcnt lgkmcnt(0)" ::: "memory")
#define LGKM8  asm volatile("s_waitcnt lgkmcnt(8)" ::: "memory")
#define SBAR   __builtin_amdgcn_s_barrier()
#define SCHED0 __builtin_amdgcn_sched_barrier(0)
#define MFMA16(af, bf, cf) __builtin_amdgcn_mfma_f32_16x16x32_bf16(af, bf, cf, 0, 0, 0)

__device__ __forceinline__ u16 f2bf(float f) {
  unsigned u = __builtin_bit_cast(unsigned, f);
  u += 0x7fffu + ((u >> 16) & 1u);   // round-to-nearest-even
  return (u16)(u >> 16);
}

__device__ __forceinline__ void gload16(const void* g, const u16* lds) {
  as1_u32p gp = (as1_u32p)(uintptr_t)g;
  as3_u32p lp = (as3_u32p)(unsigned)(uintptr_t)lds;
  __builtin_amdgcn_global_load_lds(gp, lp, 16, 0, 0);
}

// ---------------- router + x->bf16 ----------------
__global__ __launch_bounds__(256) void router_kernel(
    const float* __restrict__ x, const float* __restrict__ Wr,
    float* __restrict__ CwT, u16* __restrict__ Xb) {
  const int l = threadIdx.x & 63;
  const int t = blockIdx.x * 4 + (threadIdx.x >> 6);
  const float* xr = x + (size_t)t * 2048;
  u16* xbr = Xb + (size_t)t * 2048;
  float p[8] = {0.f,0.f,0.f,0.f,0.f,0.f,0.f,0.f};
#pragma unroll
  for (int it = 0; it < 8; ++it) {
    const int d0 = it * 256 + l * 4;
    const float4 xv = *(const float4*)(xr + d0);
    unsigned lo = (unsigned)f2bf(xv.x) | ((unsigned)f2bf(xv.y) << 16);
    unsigned hi = (unsigned)f2bf(xv.z) | ((unsigned)f2bf(xv.w) << 16);
    *(unsigned*)(xbr + d0) = lo;
    *(unsigned*)(xbr + d0 + 2) = hi;
    const float xs[4] = {xv.x, xv.y, xv.z, xv.w};
#pragma unroll
    for (int jj = 0; jj < 4; ++jj) {
      const float4 w0 = *(const float4*)(Wr + (size_t)(d0 + jj) * 8);
      const float4 w1 = *(const float4*)(Wr + (size_t)(d0 + jj) * 8 + 4);
      p[0] += xs[jj] * w0.x; p[1] += xs[jj] * w0.y;
      p[2] += xs[jj] * w0.z; p[3] += xs[jj] * w0.w;
      p[4] += xs[jj] * w1.x; p[5] += xs[jj] * w1.y;
      p[6] += xs[jj] * w1.z; p[7] += xs[jj] * w1.w;
    }
  }
#pragma unroll
  for (int e = 0; e < 8; ++e) {
    float v = p[e];
#pragma unroll
    for (int off = 32; off > 0; off >>= 1) v += __shfl_xor(v, off, 64);
    p[e] = v;
  }
  constexpr float INV_TEMP = 0.36787944117144233f;  // 1/e
  float mx = -1e30f;
#pragma unroll
  for (int e = 0; e < 8; ++e) { p[e] *= INV_TEMP; mx = fmaxf(mx, p[e]); }
  float sum = 0.f;
#pragma unroll
  for (int e = 0; e < 8; ++e) { p[e] = __expf(p[e] - mx); sum += p[e]; }
  const float inv_sum = 1.f / sum;
#pragma unroll
  for (int e = 0; e < 8; ++e) p[e] *= inv_sum;
  // drop the 3 smallest probs (ties: drop higher index, matching top_k)
  unsigned sel = 0xFFu;
  for (int it = 0; it < 3; ++it) {
    float mn = 1e30f; int mi = 0;
#pragma unroll
    for (int e = 0; e < 8; ++e)
      if ((sel >> e) & 1u) { if (p[e] <= mn) { mn = p[e]; mi = e; } }
    sel &= ~(1u << mi);
  }
  float wsum = 0.f;
#pragma unroll
  for (int e = 0; e < 8; ++e) if ((sel >> e) & 1u) wsum += p[e];
  const float inv_w = 1.f / (wsum + 1e-8f);
  if (l == 0) {
#pragma unroll
    for (int e = 0; e < 8; ++e) {
      float v = ((sel >> e) & 1u) ? p[e] * inv_w : 0.f;
      CwT[(size_t)e * 8192 + t] = (e < 4) ? v : -v;
    }
  }
}

// ---------------- transpose + fp32->bf16 ----------------
__global__ __launch_bounds__(256) void tcvt_kernel(
    const float* __restrict__ in, u16* __restrict__ out,
    int R, int C, long long ZO, long long CS) {
  __shared__ float tile[32][33];
  const int z = blockIdx.z;
  const float* ib = in + (size_t)z * R * C;
  const int r0 = blockIdx.y * 32, c0 = blockIdx.x * 32;
  const int tx = threadIdx.x, ty = threadIdx.y;  // 32 x 8
#pragma unroll
  for (int j = 0; j < 4; ++j)
    tile[ty + j * 8][tx] = ib[(size_t)(r0 + ty + j * 8) * C + c0 + tx];
  __syncthreads();
#pragma unroll
  for (int j = 0; j < 4; ++j)
    out[(size_t)z * ZO + (size_t)(c0 + ty + j * 8) * CS + r0 + tx] =
        f2bf(tile[tx][ty + j * 8]);
}

// =========== 8-phase 256-wide GEMMs (T1+T2+T3+T4+T5 stack) ===========
// Stage unit = 16KB = 128 rows x 64 k bf16, 2 x global_load_lds(16B)/thread.
// Units/K-tile: {0:Bg/B0, 1:Bu/B1, 2:A0, 3:A1}. Unit j of tile t is staged
// >=1 trailing barrier after its last reader (u0:ph0/ph1(t+2); u1:ph1/ph2;
// u2:ph0,2/ph3; u3:ph0,2/ph0(t+1,opposite buffer)).
// T2 swizzle: LDS granule (row,c) holds global granule c^(row&7); readers
// XOR the same -> 2-way max bank aliasing (free per m136).

// -------- GEMM1 persistent: 256 blocks x 4 items, dual G/U, BM=256 BN=128 --
__global__ __launch_bounds__(512, 2) void gemm1_8p(
    const u16* __restrict__ Xb, const u16* __restrict__ Wgt,
    const u16* __restrict__ Wut, const float* __restrict__ CwT,
    u16* __restrict__ Hp, int p) {
  extern __shared__ u16 lds[];  // 65536 u16 = 128KB: 2 buf x 4 units x 8192
  const int tid = threadIdx.x;
  const int l = tid & 63, w = tid >> 6;
  const int wr = w >> 2, wc = w & 3;      // 2(M) x 4(N) waves; per-wave 128x32
  const int lq = l >> 4, lr = l & 15;
  const int b = blockIdx.x;               // 256 blocks
  const int xcd = b & 7;
  const int mtile = b >> 3;               // fixed per block
  const int en0 = xcd * 4;                // items sweep en0..en0+3
  const u16* gA  = Xb + (size_t)mtile * 256 * 2048;
  const u16* s2p = gA;                       // A rows 0-127
  const u16* s3p = gA + (size_t)128 * 2048;  // A rows 128-255

  // per-thread invariant staging offsets (stride 2048 for A and B panels)
  const int row0 = tid >> 3,          cg0 = (tid & 7) ^ (row0 & 7);
  const int row1 = (512 + tid) >> 3,  cg1 = ((512 + tid) & 7) ^ (row1 & 7);
  const int off0 = row0 * 2048 + cg0 * 8;
  const int off1 = row1 * 2048 + cg1 * 8;
  const int d0e = tid * 8, d1e = (512 + tid) * 8;

  auto bptr = [&](const u16* base, int item) -> const u16* {
    const int it = item > 3 ? 3 : item;
    const int en = en0 + it;
    return base + (size_t)(p * 4 + (en >> 3)) * 2097152 +
           (size_t)(en & 7) * 128 * 2048;
  };

  auto stageV = [&](int vt2, const u16* srcb, int u) {
    if (vt2 >= 128) return;
    u16* dst = lds + (vt2 & 1) * 32768 + u * 8192;
    const int kt = (vt2 & 31) * 64;
    gload16(srcb + (size_t)(off0 + kt), dst + d0e);
    gload16(srcb + (size_t)(off1 + kt), dst + d1e);
  };

  const int xr = lr & 7;
  const int x0 = (lq ^ xr) * 8;
  const int x1 = ((4 + lq) ^ xr) * 8;
  const int aB = (2 + wr) * 8192 + lr * 64;            // + mi*1024 + x
  const int gBo = (wc * 32 + lr) * 64;                 // Bg: + ni*1024 + x
  const int uBo = 8192 + (wc * 32 + lr) * 64;          // Bu

  bf16x8 a[8][2], bg[2][2], bu[2][2];
  f32x4 ag[8][2], au[8][2];
#pragma unroll
  for (int mi = 0; mi < 8; ++mi)
#pragma unroll
    for (int ni = 0; ni < 2; ++ni) {
      ag[mi][ni] = (f32x4){0.f, 0.f, 0.f, 0.f};
      au[mi][ni] = (f32x4){0.f, 0.f, 0.f, 0.f};
    }

  // staging B sources (switch to next item at t==30)
  const u16* bgS = bptr(Wgt, 0);
  const u16* buS = bptr(Wut, 0);
  int item_c = 0;                 // current item for epilogue

  // prologue: vt0 units 0-3, vt1 units 0-2 (7 stages); vmcnt(6) -> vt0 in
  stageV(0, bgS, 0); stageV(0, buS, 1); stageV(0, s2p, 2); stageV(0, s3p, 3);
  stageV(1, bgS, 0); stageV(1, buS, 1); stageV(1, s2p, 2);
  VMCNT6; SBAR;

  for (int vt = 0; vt < 128; ++vt) {
    const int t = vt & 31;
    if (t == 30) { bgS = bptr(Wgt, item_c + 1); buS = bptr(Wut, item_c + 1); }
    const u16* Lb = lds + (vt & 1) * 32768;
    // phase 0: read a[0-3], bg; stage A1(vt+1); MFMA G m0-3
    {
#pragma unroll
      for (int mi = 0; mi < 4; ++mi) {
        a[mi][0] = *(const bf16x8*)&Lb[aB + mi * 1024 + x0];
        a[mi][1] = *(const bf16x8*)&Lb[aB + mi * 1024 + x1];
      }
#pragma unroll
      for (int ni = 0; ni < 2; ++ni) {
        bg[ni][0] = *(const bf16x8*)&Lb[gBo + ni * 1024 + x0];
        bg[ni][1] = *(const bf16x8*)&Lb[gBo + ni * 1024 + x1];
      }
      stageV(vt + 1, s3p, 3);
      LGKM8; SBAR; LGKM0; SCHED0;
      __builtin_amdgcn_s_setprio(1);
#pragma unroll
      for (int mi = 0; mi < 4; ++mi)
#pragma unroll
        for (int ni = 0; ni < 2; ++ni)
#pragma unroll
          for (int kk = 0; kk < 2; ++kk)
            ag[mi][ni] = MFMA16(a[mi][kk], bg[ni][kk], ag[mi][ni]);
      __builtin_amdgcn_s_setprio(0); SCHED0; SBAR;
    }
    // phase 1: read bu; stage Bg(vt+2); MFMA U m0-3
    {
#pragma unroll
      for (int ni = 0; ni < 2; ++ni) {
        bu[ni][0] = *(const bf16x8*)&Lb[uBo + ni * 1024 + x0];
        bu[ni][1] = *(const bf16x8*)&Lb[uBo + ni * 1024 + x1];
      }
      stageV(vt + 2, bgS, 0);
      SBAR; LGKM0; SCHED0;
      __builtin_amdgcn_s_setprio(1);
#pragma unroll
      for (int mi = 0; mi < 4; ++mi)
#pragma unroll
        for (int ni = 0; ni < 2; ++ni)
#pragma unroll
          for (int kk = 0; kk < 2; ++kk)
            au[mi][ni] = MFMA16(a[mi][kk], bu[ni][kk], au[mi][ni]);
      __builtin_amdgcn_s_setprio(0); SCHED0; SBAR;
    }
    // phase 2: read a[4-7]; stage Bu(vt+2); MFMA G m4-7
    {
#pragma unroll
      for (int mi = 4; mi < 8; ++mi) {
        a[mi][0] = *(const bf16x8*)&Lb[aB + mi * 1024 + x0];
        a[mi][1] = *(const bf16x8*)&Lb[aB + mi * 1024 + x1];
      }
      stageV(vt + 2, buS, 1);
      SBAR; LGKM0; SCHED0;
      __builtin_amdgcn_s_setprio(1);
#pragma unroll
      for (int mi = 4; mi < 8; ++mi)
#pragma unroll
        for (int ni = 0; ni < 2; ++ni)
#pragma unroll
          for (int kk = 0; kk < 2; ++kk)
            ag[mi][ni] = MFMA16(a[mi][kk], bg[ni][kk], ag[mi][ni]);
      __builtin_amdgcn_s_setprio(0); SCHED0; SBAR;
    }
    // phase 3: stage A0(vt+2); vmcnt; MFMA U m4-7
    {
      stageV(vt + 2, s2p, 2);
      if (vt < 126) { VMCNT6; } else if (vt == 126) { VMCNT0; }
      SBAR; LGKM0; SCHED0;
      __builtin_amdgcn_s_setprio(1);
#pragma unroll
      for (int mi = 4; mi < 8; ++mi)
#pragma unroll
        for (int ni = 0; ni < 2; ++ni)
#pragma unroll
          for (int kk = 0; kk < 2; ++kk)
            au[mi][ni] = MFMA16(a[mi][kk], bu[ni][kk], au[mi][ni]);
      __builtin_amdgcn_s_setprio(0); SCHED0; SBAR;
    }
    // item boundary: epilogue (no LDS), reset acc
    if (t == 31) {
      const int en = en0 + item_c;
      const int el = en >> 3, nt = en & 7, e = p * 4 + el;
      const float* cb = CwT + (size_t)e * 8192 + mtile * 256;
#pragma unroll
      for (int mi = 0; mi < 8; ++mi) {
        const int r0 = wr * 128 + mi * 16 + lq * 4;
        const float4 c4 = *(const float4*)(cb + r0);
        const float cs[4] = {c4.x, c4.y, c4.z, c4.w};
#pragma unroll
        for (int j = 0; j < 4; ++j) {
          const size_t row = (size_t)mtile * 256 + r0 + j;
#pragma unroll
          for (int ni = 0; ni < 2; ++ni) {
            const float g = ag[mi][ni][j], u = au[mi][ni][j];
            const float h = g * (1.f / (1.f + __expf(-g))) * u * cs[j];
            Hp[row * 4096 + el * 1024 + nt * 128 + wc * 32 + ni * 16 + lr] =
                f2bf(h);
          }
        }
      }
      ++item_c;
#pragma unroll
      for (int mi = 0; mi < 8; ++mi)
#pragma unroll
        for (int ni = 0; ni < 2; ++ni) {
          ag[mi][ni] = (f32x4){0.f, 0.f, 0.f, 0.f};
          au[mi][ni] = (f32x4){0.f, 0.f, 0.f, 0.f};
        }
    }
  }
}

// ---------------- GEMM2 (BM=BN=256, out (+)= H' @ Wdt[:,koff..]) ----------
__global__ __launch_bounds__(512, 2) void gemm2_8p(
    const u16* __restrict__ Hp, const u16* __restrict__ Wdt,
    float* __restrict__ out, int koff, int accum) {
  extern __shared__ u16 lds[];
  const int tid = threadIdx.x;
  const int l = tid & 63, w = tid >> 6;
  const int wr = w >> 2, wc = w & 3;      // per-wave 128x64
  const int lq = l >> 4, lr = l & 15;
  const int bid = blockIdx.x;             // 256 blocks
  const int work = (bid & 7) * 32 + (bid >> 3);
  const int mtile = work & 31, ntile = work >> 5;   // 32 x 8
  const u16* gA = Hp + (size_t)mtile * 256 * 4096;             // stride 4096
  const u16* gB = Wdt + (size_t)ntile * 256 * 8192 + koff;     // stride 8192
  const u16* s0p = gB;                       // B rows 0-127
  const u16* s1p = gB + (size_t)128 * 8192;  // B rows 128-255
  const u16* s2p = gA;                       // A rows 0-127
  const u16* s3p = gA + (size_t)128 * 4096;  // A rows 128-255
  const int NT = 64;                         // K = 4096

  const int row0 = tid >> 3,          cg0 = (tid & 7) ^ (row0 & 7);
  const int row1 = (512 + tid) >> 3,  cg1 = ((512 + tid) & 7) ^ (row1 & 7);
  const int offA0 = row0 * 4096 + cg0 * 8, offA1 = row1 * 4096 + cg1 * 8;
  const int offB0 = row0 * 8192 + cg0 * 8, offB1 = row1 * 8192 + cg1 * 8;
  const int d0e = tid * 8, d1e = (512 + tid) * 8;

  auto stageA = [&](int tt, const u16* srcb, int u) {
    if (tt >= NT) return;
    u16* dst = lds + (tt & 1) * 32768 + u * 8192;
    const int kt = tt * 64;
    gload16(srcb + (size_t)(offA0 + kt), dst + d0e);
    gload16(srcb + (size_t)(offA1 + kt), dst + d1e);
  };
  auto stageB = [&](int tt, const u16* srcb, int u) {
    if (tt >= NT) return;
    u16* dst = lds + (tt & 1) * 32768 + u * 8192;
    const int kt = tt * 64;
    gload16(srcb + (size_t)(offB0 + kt), dst + d0e);
    gload16(srcb + (size_t)(offB1 + kt), dst + d1e);
  };

  const int xr = lr & 7;
  const int x0 = (lq ^ xr) * 8;
  const int x1 = ((4 + lq) ^ xr) * 8;
  const int aB = (2 + wr) * 8192 + lr * 64;                    // + mi*1024
  const int bB = (wc >> 1) * 8192 + ((wc & 1) * 64 + lr) * 64; // + ni*1024

  bf16x8 a[8][2], b[4][2];
  f32x4 acc[8][4];
#pragma unroll
  for (int mi = 0; mi < 8; ++mi)
#pragma unroll
    for (int ni = 0; ni < 4; ++ni) acc[mi][ni] = (f32x4){0.f, 0.f, 0.f, 0.f};

  stageB(0, s0p, 0); stageB(0, s1p, 1); stageA(0, s2p, 2); stageA(0, s3p, 3);
  stageB(1, s0p, 0); stageB(1, s1p, 1); stageA(1, s2p, 2);
  VMCNT6; SBAR;

  for (int t = 0; t < NT; ++t) {
    const u16* Lb = lds + (t & 1) * 32768;
    // phase 0: read a[0-3], b[0-1] (+wc<2: b[2-3]); stage A1(t+1); MFMA m0-3 n0-1
    {
#pragma unroll
      for (int mi = 0; mi < 4; ++mi) {
        a[mi][0] = *(const bf16x8*)&Lb[aB + mi * 1024 + x0];
        a[mi][1] = *(const bf16x8*)&Lb[aB + mi * 1024 + x1];
      }
#pragma unroll
      for (int ni = 0; ni < 2; ++ni) {
        b[ni][0] = *(const bf16x8*)&Lb[bB + ni * 1024 + x0];
        b[ni][1] = *(const bf16x8*)&Lb[bB + ni * 1024 + x1];
      }
      if (wc < 2) {
#pragma unroll
        for (int ni = 2; ni < 4; ++ni) {
          b[ni][0] = *(const bf16x8*)&Lb[bB + ni * 1024 + x0];
          b[ni][1] = *(const bf16x8*)&Lb[bB + ni * 1024 + x1];
        }
      }
      stageA(t + 1, s3p, 3);
      LGKM8; SBAR; LGKM0; SCHED0;
      __builtin_amdgcn_s_setprio(1);
#pragma unroll
      for (int mi = 0; mi < 4; ++mi)
#pragma unroll
        for (int ni = 0; ni < 2; ++ni)
#pragma unroll
          for (int kk = 0; kk < 2; ++kk)
            acc[mi][ni] = MFMA16(a[mi][kk], b[ni][kk], acc[mi][ni]);
      __builtin_amdgcn_s_setprio(0); SCHED0; SBAR;
    }
    // phase 1: wc>=2 read b[2-3]; stage B0(t+2); MFMA m0-3 n2-3
    {
      if (wc >= 2) {
#pragma unroll
        for (int ni = 2; ni < 4; ++ni) {
          b[ni][0] = *(const bf16x8*)&Lb[bB + ni * 1024 + x0];
          b[ni][1] = *(const bf16x8*)&Lb[bB + ni * 1024 + x1];
        }
      }
      stageB(t + 2, s0p, 0);
      SBAR; LGKM0; SCHED0;
      __builtin_amdgcn_s_setprio(1);
#pragma unroll
      for (int mi = 0; mi < 4; ++mi)
#pragma unroll
        for (int ni = 2; ni < 4; ++ni)
#pragma unroll
          for (int kk = 0; kk < 2; ++kk)
            acc[mi][ni] = MFMA16(a[mi][kk], b[ni][kk], acc[mi][ni]);
      __builtin_amdgcn_s_setprio(0); SCHED0; SBAR;
    }
    // phase 2: read a[4-7]; stage B1(t+2); MFMA m4-7 n2-3
    {
#pragma unroll
      for (int mi = 4; mi < 8; ++mi) {
        a[mi][0] = *(const bf16x8*)&Lb[aB + mi * 1024 + x0];
        a[mi][1] = *(const bf16x8*)&Lb[aB + mi * 1024 + x1];
      }
      stageB(t + 2, s1p, 1);
      SBAR; LGKM0; SCHED0;
      __builtin_amdgcn_s_setprio(1);
#pragma unroll
      for (int mi = 4; mi < 8; ++mi)
#pragma unroll
        for (int ni = 2; ni < 4; ++ni)
#pragma unroll
          for (int kk = 0; kk < 2; ++kk)
            acc[mi][ni] = MFMA16(a[mi][kk], b[ni][kk], acc[mi][ni]);
      __builtin_amdgcn_s_setprio(0); SCHED0; SBAR;
    }
    // phase 3: stage A0(t+2); vmcnt; MFMA m4-7 n0-1
    {
      stageA(t + 2, s2p, 2);
      if (t < NT - 2) { VMCNT6; } else if (t == NT - 2) { VMCNT0; }
      SBAR; LGKM0; SCHED0;
      __builtin_amdgcn_s_setprio(1);
#pragma unroll
      for (int mi = 4; mi < 8; ++mi)
#pragma unroll
        for (int ni = 0; ni < 2; ++ni)
#pragma unroll
          for (int kk = 0; kk < 2; ++kk)
            acc[mi][ni] = MFMA16(a[mi][kk], b[ni][kk], acc[mi][ni]);
      __builtin_amdgcn_s_setprio(0); SCHED0; SBAR;
    }
  }

#pragma unroll
  for (int mi = 0; mi < 8; ++mi)
#pragma unroll
    for (int ni = 0; ni < 4; ++ni)
#pragma unroll
      for (int j = 0; j < 4; ++j) {
        const int row = mtile * 256 + wr * 128 + mi * 16 + lq * 4 + j;
        const int col = ntile * 256 + wc * 64 + ni * 16 + lr;
        const size_t idx = (size_t)row * 2048 + col;
        float v = acc[mi][ni][j];
        if (accum) v += out[idx];
        out[idx] = v;
      }
}

// ---------------- tension scalar: mean(output^2) ----------------
__global__ __launch_bounds__(256) void sqsum_partial(
    const float* __restrict__ out, float* __restrict__ part, int n4) {
  float s = 0.f;
  const int idx = blockIdx.x * 256 + threadIdx.x;
  const int stride = gridDim.x * 256;
  for (int i = idx; i < n4; i += stride) {
    const float4 v = ((const float4*)out)[i];
    s += v.x * v.x + v.y * v.y + v.z * v.z + v.w * v.w;
  }
#pragma unroll
  for (int off = 32; off > 0; off >>= 1) s += __shfl_down(s, off, 64);
  __shared__ float ls[4];
  if ((threadIdx.x & 63) == 0) ls[threadIdx.x >> 6] = s;
  __syncthreads();
  if (threadIdx.x == 0) part[blockIdx.x] = ls[0] + ls[1] + ls[2] + ls[3];
}

__global__ __launch_bounds__(256) void sqsum_final(
    const float* __restrict__ part, float* __restrict__ dst, int np, float scale) {
  float s = 0.f;
  for (int i = threadIdx.x; i < np; i += 256) s += part[i];
#pragma unroll
  for (int off = 32; off > 0; off >>= 1) s += __shfl_down(s, off, 64);
  __shared__ float ls[4];
  if ((threadIdx.x & 63) == 0) ls[threadIdx.x >> 6] = s;
  __syncthreads();
  if (threadIdx.x == 0) dst[0] = (ls[0] + ls[1] + ls[2] + ls[3]) * scale;
}

// ---------------- launch ----------------
extern "C" void kernel_launch(void* const* d_in, const int* in_sizes, int n_in,
                              void* d_out, int out_size, void* d_ws, size_t ws_size,
                              hipStream_t stream) {
  (void)in_sizes; (void)n_in; (void)out_size; (void)ws_size;
  const float* x  = (const float*)d_in[0];
  const float* Wr = (const float*)d_in[1];
  const float* Wg = (const float*)d_in[2];
  const float* Wu = (const float*)d_in[3];
  const float* Wd = (const float*)d_in[4];
  float* out = (float*)d_out;
  char* ws = (char*)d_ws;
  u16*   Xb   = (u16*)(ws);
  u16*   Wgt  = (u16*)(ws + 33554432);
  u16*   Wut  = (u16*)(ws + 67108864);
  u16*   Wdt  = (u16*)(ws + 100663296);
  u16*   Hp   = (u16*)(ws + 134217728);
  float* CwT  = (float*)(ws + 201326592);
  float* part = (float*)(ws + 201588736);

  (void)hipFuncSetAttribute((const void*)gemm1_8p,
                            hipFuncAttributeMaxDynamicSharedMemorySize, 131072);
  (void)hipFuncSetAttribute((const void*)gemm2_8p,
                            hipFuncAttributeMaxDynamicSharedMemorySize, 131072);

  router_kernel<<<2048, 256, 0, stream>>>(x, Wr, CwT, Xb);

  dim3 tb(32, 8);
  tcvt_kernel<<<dim3(32, 64, 8), tb, 0, stream>>>(Wg, Wgt, 2048, 1024, 2097152LL, 2048LL);
  tcvt_kernel<<<dim3(32, 64, 8), tb, 0, stream>>>(Wu, Wut, 2048, 1024, 2097152LL, 2048LL);
  tcvt_kernel<<<dim3(64, 32, 8), tb, 0, stream>>>(Wd, Wdt, 1024, 2048, 1024LL, 8192LL);

  for (int p = 0; p < 2; ++p) {
    gemm1_8p<<<256, 512, 131072, stream>>>(Xb, Wgt, Wut, CwT, Hp, p);
    gemm2_8p<<<256, 512, 131072, stream>>>(Hp, Wdt, out, p * 4096, p);
  }

  sqsum_partial<<<1024, 256, 0, stream>>>(out, part, 16777216 / 4);
  sqsum_final<<<1, 256, 0, stream>>>(part, out + 16777216, 1024, 1.f / 16777216.f);
}